// Round 24
// baseline (120.130 us; speedup 1.0000x reference)
//
#include <hip/hip_runtime.h>
#include <stdint.h>

typedef __attribute__((ext_vector_type(4))) float f32x4;
typedef __attribute__((ext_vector_type(8))) short bf16x8;

#define AS1(p) ((const __attribute__((address_space(1))) void*)(p))
#define AS3(p) ((__attribute__((address_space(3))) void*)(p))

__device__ __forceinline__ unsigned short f2bf(float f){
  unsigned u = __builtin_bit_cast(unsigned, f);
  u += 0x7FFF + ((u >> 16) & 1);     // round-to-nearest-even
  return (unsigned short)(u >> 16);
}

template<int N> __device__ __forceinline__ void waitcnt_vm(){
  if constexpr (N==0) asm volatile("s_waitcnt vmcnt(0)" ::: "memory");
  else if constexpr (N==2) asm volatile("s_waitcnt vmcnt(2)" ::: "memory");
  else if constexpr (N==3) asm volatile("s_waitcnt vmcnt(3)" ::: "memory");
  else if constexpr (N==4) asm volatile("s_waitcnt vmcnt(4)" ::: "memory");
  else if constexpr (N==6) asm volatile("s_waitcnt vmcnt(6)" ::: "memory");
}

// ================= KNN grid geometry ======================================
#define GD 14
#define NL 8192

__device__ __forceinline__ int cellcoord(float x){
  int c = (int)(x * (float)GD);
  return min(GD-1, max(0, c));
}

// ---------- k_pre: 3 weight transposes (z<3) + grid build (z==3) -----------
__global__ __launch_bounds__(256) void k_pre(const float* __restrict__ W1,
                                             const float* __restrict__ W2,
                                             const float* __restrict__ W3,
                                             unsigned short* __restrict__ W1t,
                                             unsigned short* __restrict__ W2t,
                                             unsigned short* __restrict__ W3t,
                                             const float* __restrict__ l_pos,
                                             int* __restrict__ cellStart,
                                             float4* __restrict__ sorted){
  const int z = blockIdx.z;
  if (z == 3){
    if (blockIdx.x != 0 || blockIdx.y != 0) return;
    __shared__ int hist[4096];
    __shared__ int cur[4096];
    __shared__ int s[256];
    const int t = threadIdx.x;
    #pragma unroll
    for (int k = 0; k < 16; k++) hist[k*256 + t] = 0;
    __syncthreads();
    for (int k = 0; k < 32; k++){
      int i = k*256 + t;
      float x = l_pos[3*i], y = l_pos[3*i+1], zz = l_pos[3*i+2];
      int c = (cellcoord(zz)*GD + cellcoord(y))*GD + cellcoord(x);
      atomicAdd(&hist[c], 1);
    }
    __syncthreads();
    int loc[16]; int sum = 0;
    #pragma unroll
    for (int e = 0; e < 16; e++){ loc[e] = hist[t*16 + e]; sum += loc[e]; }
    s[t] = sum;
    __syncthreads();
    for (int off = 1; off < 256; off <<= 1){
      int val = (t >= off) ? s[t-off] : 0;
      __syncthreads();
      s[t] += val;
      __syncthreads();
    }
    int base = s[t] - sum;
    #pragma unroll
    for (int e = 0; e < 16; e++){
      cellStart[t*16 + e] = base;
      cur[t*16 + e] = base;
      base += loc[e];
    }
    __syncthreads();
    for (int k = 0; k < 32; k++){
      int i = k*256 + t;
      float x = l_pos[3*i], y = l_pos[3*i+1], zz = l_pos[3*i+2];
      int c = (cellcoord(zz)*GD + cellcoord(y))*GD + cellcoord(x);
      int slot = atomicAdd(&cur[c], 1);
      float4 q; q.x = x; q.y = y; q.z = zz; q.w = __int_as_float(i);
      sorted[slot] = q;
    }
    return;
  }
  const float* in; unsigned short* out; int R, C;
  if (z == 0){ in = W1; out = W1t; R = 512; C = 512; }
  else if (z == 1){ in = W2; out = W2t; R = 512; C = 512; }
  else { in = W3; out = W3t; R = 512; C = 128; if (blockIdx.x >= 4) return; }
  __shared__ float tile[32][33];
  int tx = threadIdx.x & 31, ty = threadIdx.x >> 5;       // 32 x 8
  int c0 = blockIdx.x*32, r0 = blockIdx.y*32;
  #pragma unroll
  for (int i = 0; i < 4; i++)
    tile[ty + i*8][tx] = in[(size_t)(r0 + ty + i*8)*C + c0 + tx];
  __syncthreads();
  #pragma unroll
  for (int i = 0; i < 4; i++)
    out[(size_t)(c0 + ty + i*8)*R + r0 + tx] = f2bf(tile[tx][ty + i*8]);
}

// ======== GEMM core (R13/R16 proven loop): BM x NC, 3-buf counted-vmcnt ====
// ds_reads at step top, stage t+2 mid, setprio MFMA, counted vmcnt at tail,
// one barrier/step. Chunk swizzle c^((row>>1)&3) both-sides, dest linear.
// AF32: A f32, reg-staged (load early, f2bf+ds_write at tail).
// ADDOUT: out = acc + bias + out_prev (fused knn-interp add).
template<int BM, int NC, int TW, bool AF32, bool RELU, bool OUTBF16, bool ADDOUT>
__device__ __forceinline__ void gemm_core(int bm, int bn, int NOUT,
                                          const void* __restrict__ Av,
                                          const unsigned short* __restrict__ Bt,
                                          const float* __restrict__ bias,
                                          void* __restrict__ out, int K){
  constexpr int WARPS_M = BM/64;
  constexpr int WARPS_N = (TW/64)/WARPS_M;
  constexpr int WN = NC/WARPS_N;
  constexpr int NI = WN/16;
  constexpr int IA = AF32 ? 0 : (BM*4)/TW;
  constexpr int IB = (NC*4)/TW;
  constexpr int LS = IA + IB;

  __shared__ short As[3][BM*32];
  __shared__ short Bs[3][NC*32];

  const int tid  = threadIdx.x;
  const int lane = tid & 63, wid = tid >> 6;
  const int wr = wid / WARPS_N, wc = wid % WARPS_N;
  const int l15 = lane & 15, lk = lane >> 4;

  const unsigned short* Bsrc[IB];
  #pragma unroll
  for (int q = 0; q < IB; q++){
    int row = q*(TW/4) + (tid >> 2);
    int ch  = (tid & 3) ^ ((row >> 1) & 3);
    Bsrc[q] = Bt + (size_t)bn*NC*K + (size_t)row*K + ch*8;
  }
  const unsigned short* Asrc16[IA > 0 ? IA : 1];
  if constexpr (!AF32){
    #pragma unroll
    for (int a = 0; a < IA; a++){
      int row = a*(TW/4) + (tid >> 2);
      int ch  = (tid & 3) ^ ((row >> 1) & 3);
      Asrc16[a] = (const unsigned short*)Av + (size_t)bm*BM*K + (size_t)row*K + ch*8;
    }
  }
  const float* A32 = (const float*)Av + (size_t)bm*BM*K + (size_t)(tid>>2)*K + (size_t)(tid&3)*8;
  const int woff = (tid >> 2)*32 + ((tid & 3) ^ (((tid >> 2) >> 1) & 3))*8;

#define STAGE_B(t_, bb_) do{ int k0_ = (t_) << 5; _Pragma("unroll") \
  for (int q = 0; q < IB; q++) \
    __builtin_amdgcn_global_load_lds(AS1(Bsrc[q] + k0_), AS3(&Bs[bb_][(q*(TW/4))*32 + tid*8]), 16, 0, 0); \
}while(0)
#define STAGE_A16(t_, bb_) do{ int k0_ = (t_) << 5; _Pragma("unroll") \
  for (int a = 0; a < IA; a++) \
    __builtin_amdgcn_global_load_lds(AS1(Asrc16[a] + k0_), AS3(&As[bb_][(a*(TW/4))*32 + tid*8]), 16, 0, 0); \
}while(0)
#define A_CONV_WRITE(bb_) do{ bf16x8 p_; _Pragma("unroll") \
  for (int j_ = 0; j_ < 4; j_++){ p_[j_] = (short)f2bf(ra0[j_]); p_[j_+4] = (short)f2bf(ra1[j_]); } \
  *(bf16x8*)&As[bb_][woff] = p_; \
}while(0)

  f32x4 acc[4][NI];
  #pragma unroll
  for (int i = 0; i < 4; i++)
    #pragma unroll
    for (int j = 0; j < NI; j++) acc[i][j] = (f32x4){0.f,0.f,0.f,0.f};

  const int nt = K >> 5;
  f32x4 ra0, ra1;

  if constexpr (AF32){
    ra0 = *(const f32x4*)(A32);
    ra1 = *(const f32x4*)(A32 + 4);
    STAGE_B(0, 0);
    STAGE_B(1, 1);
    waitcnt_vm<IB>();
    A_CONV_WRITE(0);
    asm volatile("s_waitcnt lgkmcnt(0)" ::: "memory");
  } else {
    STAGE_A16(0, 0); STAGE_B(0, 0);
    STAGE_A16(1, 1); STAGE_B(1, 1);
    waitcnt_vm<LS>();
  }
  __builtin_amdgcn_s_barrier();

  int b = 0;
  for (int t = 0; t < nt; ++t){
    bf16x8 af[4], bg[NI];
    #pragma unroll
    for (int i = 0; i < 4; i++){
      int R = wr*64 + i*16 + l15;
      af[i] = *(const bf16x8*)&As[b][R*32 + (lk ^ ((R >> 1) & 3))*8];
    }
    #pragma unroll
    for (int j = 0; j < NI; j++){
      int R = wc*WN + j*16 + l15;
      bg[j] = *(const bf16x8*)&Bs[b][R*32 + (lk ^ ((R >> 1) & 3))*8];
    }

    int b2 = b + 2; if (b2 >= 3) b2 -= 3;
    if constexpr (AF32){
      if (t + 1 < nt){
        int k1 = (t + 1) << 5;
        ra0 = *(const f32x4*)(A32 + k1);
        ra1 = *(const f32x4*)(A32 + k1 + 4);
      }
      if (t + 2 < nt) STAGE_B(t + 2, b2);
    } else {
      if (t + 2 < nt){ STAGE_A16(t + 2, b2); STAGE_B(t + 2, b2); }
    }

    __builtin_amdgcn_s_setprio(1);
    #pragma unroll
    for (int i = 0; i < 4; i++)
      #pragma unroll
      for (int j = 0; j < NI; j++)
        acc[i][j] = __builtin_amdgcn_mfma_f32_16x16x32_bf16(af[i], bg[j], acc[i][j], 0, 0, 0);
    __builtin_amdgcn_s_setprio(0);

    if (t + 2 < nt) waitcnt_vm<(AF32 ? IB : LS)>();
    else            waitcnt_vm<0>();
    if constexpr (AF32){
      if (t + 1 < nt){
        int wb = b + 1; if (wb >= 3) wb -= 3;
        A_CONV_WRITE(wb);
      }
    }
    asm volatile("s_waitcnt lgkmcnt(0)" ::: "memory");
    __builtin_amdgcn_s_barrier();
    b = (b + 1 == 3) ? 0 : b + 1;
  }
#undef STAGE_B
#undef STAGE_A16
#undef A_CONV_WRITE

  const int row0 = bm*BM + wr*64 + lk*4;
  const int col0 = bn*NC + wc*WN + l15;
  #pragma unroll
  for (int i = 0; i < 4; i++){
    #pragma unroll
    for (int j = 0; j < NI; j++){
      int col = col0 + j*16;
      float bv = bias[col];
      #pragma unroll
      for (int r = 0; r < 4; r++){
        int row = row0 + i*16 + r;
        float v = acc[i][j][r] + bv;
        if (RELU) v = fmaxf(v, 0.f);
        if (ADDOUT) v = v + ((const float*)out)[(size_t)row*NOUT + col];
        if (OUTBF16) ((unsigned short*)out)[(size_t)row*NOUT + col] = f2bf(v);
        else         ((float*)out)[(size_t)row*NOUT + col] = v;
      }
    }
  }
}

template<int BM, int NC, int TW, int MINW, bool AF32, bool RELU, bool OUTBF16, bool ADDOUT>
__global__ __launch_bounds__(TW, MINW) void k_gemm(const void* __restrict__ Av,
                                                   const unsigned short* __restrict__ Bt,
                                                   const float* __restrict__ bias,
                                                   void* __restrict__ out, int K, int NOUT){
  gemm_core<BM, NC, TW, AF32, RELU, OUTBF16, ADDOUT>(blockIdx.x, blockIdx.y, NOUT,
                                                     Av, Bt, bias, out, K);
}

// ================= KNN search + gather core ================================
// Dedup-safe + (d, index)-lexicographic insert: order-independent top-3
#define KNN_INS(dv, gi) \
  if (gi != i0 && gi != i1 && gi != i2 && \
      (dv < d2 || (dv == d2 && gi < i2))){ \
    if (dv < d1 || (dv == d1 && gi < i1)){ \
      d2 = d1; i2 = i1; \
      if (dv < d0 || (dv == d0 && gi < i0)){ d1 = d0; i1 = i0; d0 = dv; i0 = gi; } \
      else { d1 = dv; i1 = gi; } \
    } else { d2 = dv; i2 = gi; } \
  }

#define KNN_MERGE16() \
  _Pragma("unroll") \
  for (int m = 1; m < 16; m <<= 1){ \
    float e0 = __shfl_xor(d0, m), e1 = __shfl_xor(d1, m), e2 = __shfl_xor(d2, m); \
    int   j0 = __shfl_xor(i0, m), j1 = __shfl_xor(i1, m), j2 = __shfl_xor(i2, m); \
    KNN_INS(e0, j0); KNN_INS(e1, j1); KNN_INS(e2, j2); \
  }

// 16 lanes per h-point: search top-3 AND gather/interp (fused, no wts/idx).
__device__ __forceinline__ void knn_core(int h, int sl,
                                         const float* __restrict__ h_pos,
                                         const int* __restrict__ cellStart,
                                         const float4* __restrict__ sorted,
                                         const float* __restrict__ l_y,
                                         float* __restrict__ out){
  const float hx = h_pos[3*h], hy = h_pos[3*h+1], hz = h_pos[3*h+2];
  const int cx = cellcoord(hx), cy = cellcoord(hy), cz = cellcoord(hz);
  const float cs = 1.0f/(float)GD;
  float d0 = 3e38f, d1 = 3e38f, d2 = 3e38f;
  int   i0 = 0x7fffffff, i1 = 0x7fffffff, i2 = 0x7fffffff;

  for (int ci = sl; ci < 27; ci += 16){
    int dz = ci/9 - 1, dy = (ci - (ci/9)*9)/3 - 1, dx = ci % 3 - 1;
    int zz = cz+dz, yy = cy+dy, xx = cx+dx;
    if ((unsigned)zz >= GD || (unsigned)yy >= GD || (unsigned)xx >= GD) continue;
    int c = (zz*GD + yy)*GD + xx;
    int p0 = cellStart[c], p1 = cellStart[c+1];
    for (int p = p0; p < p1; p++){
      float4 qq = sorted[p];
      float ddx = hx - qq.x, ddy = hy - qq.y, ddz = hz - qq.z;
      float d = fmaf(ddx, ddx, fmaf(ddy, ddy, ddz*ddz));
      int gi = __float_as_int(qq.w);
      KNN_INS(d, gi);
    }
  }
  KNN_MERGE16();

  for (int r = 2; r < GD; r++){
    int rp = r - 1;
    float B = 3e38f;
    if (cx - rp > 0)      B = fminf(B, hx - (float)(cx-rp)*cs);
    if (cx + rp + 1 < GD) B = fminf(B, (float)(cx+rp+1)*cs - hx);
    if (cy - rp > 0)      B = fminf(B, hy - (float)(cy-rp)*cs);
    if (cy + rp + 1 < GD) B = fminf(B, (float)(cy+rp+1)*cs - hy);
    if (cz - rp > 0)      B = fminf(B, hz - (float)(cz-rp)*cs);
    if (cz + rp + 1 < GD) B = fminf(B, (float)(cz+rp+1)*cs - hz);
    if (d2 <= B*B) break;                     // group-uniform after merge

    int side = 2*r + 1, ss = side*side, tot = ss*side;
    for (int ci = sl; ci < tot; ci += 16){
      int dz = ci/ss - r;
      int rem = ci - (ci/ss)*ss;
      int dy = rem/side - r, dx = rem - (rem/side)*side - r;
      int adx = abs(dx), ady = abs(dy), adz = abs(dz);
      if (max(adx, max(ady, adz)) < r) continue;   // shell-exact
      int zz = cz+dz, yy = cy+dy, xx = cx+dx;
      if ((unsigned)zz >= GD || (unsigned)yy >= GD || (unsigned)xx >= GD) continue;
      int c = (zz*GD + yy)*GD + xx;
      int p0 = cellStart[c], p1 = cellStart[c+1];
      for (int p = p0; p < p1; p++){
        float4 qq = sorted[p];
        float ddx = hx - qq.x, ddy = hy - qq.y, ddz = hz - qq.z;
        float d = fmaf(ddx, ddx, fmaf(ddy, ddy, ddz*ddz));
        int gi = __float_as_int(qq.w);
        KNN_INS(d, gi);
      }
    }
    KNN_MERGE16();
  }

  // fused gather: lane sl handles feats [sl*8, sl*8+8) = 2 f32x4
  float w0 = 1.0f/fmaxf(d0, 1e-16f);
  float w1 = 1.0f/fmaxf(d1, 1e-16f);
  float w2 = 1.0f/fmaxf(d2, 1e-16f);
  float inv = 1.0f/(w0 + w1 + w2);
  const f32x4* ly4 = (const f32x4*)l_y;
  size_t b0 = (size_t)i0*32 + sl*2;
  size_t b1 = (size_t)i1*32 + sl*2;
  size_t b2 = (size_t)i2*32 + sl*2;
  f32x4 a0 = ly4[b0]*w0     + ly4[b1]*w1     + ly4[b2]*w2;
  f32x4 a1 = ly4[b0 + 1]*w0 + ly4[b1 + 1]*w1 + ly4[b2 + 1]*w2;
  size_t o = (size_t)h*32 + sl*2;
  ((f32x4*)out)[o]     = a0*inv;
  ((f32x4*)out)[o + 1] = a1*inv;
}

// ======== Fused GEMM1 + KNN: SEQUENTIAL block ordering ======================
// gid<512 -> GEMM1 blocks (dispatched first, fill all CUs at 2/CU with no
// knn contention); gid>=512 -> knn blocks (backfill as GEMM blocks retire,
// hiding knn in G1's ramp-down tail). Correctness is order-independent.
__global__ __launch_bounds__(512, 4) void k_g1knn(const float* __restrict__ emb,
                                                  const unsigned short* __restrict__ W1t,
                                                  const float* __restrict__ b1,
                                                  unsigned short* __restrict__ bufB,
                                                  const float* __restrict__ h_pos,
                                                  const int* __restrict__ cellStart,
                                                  const float4* __restrict__ sorted,
                                                  const float* __restrict__ l_y,
                                                  float* __restrict__ dout){
  const int gid = blockIdx.x;
  if (gid < 512){
    gemm_core<128, 256, 512, true, true, true, false>(gid >> 1, gid & 1, 512,
                                                      emb, W1t, b1, bufB, 512);
  } else {
    int k = gid - 512;                       // 0..1023
    int t = threadIdx.x;
    knn_core(k*32 + (t >> 4), t & 15, h_pos, cellStart, sorted, l_y, dout);
  }
}

extern "C" void kernel_launch(void* const* d_in, const int* in_sizes, int n_in,
                              void* d_out, int out_size, void* d_ws, size_t ws_size,
                              hipStream_t stream){
  const float* emb   = (const float*)d_in[0];
  const float* l_y   = (const float*)d_in[1];
  const float* l_pos = (const float*)d_in[2];
  const float* h_pos = (const float*)d_in[3];
  const float* W1    = (const float*)d_in[4];
  const float* b1    = (const float*)d_in[5];
  const float* W2    = (const float*)d_in[6];
  const float* b2    = (const float*)d_in[7];
  const float* W3    = (const float*)d_in[8];
  const float* b3    = (const float*)d_in[9];

  const int M = 32768, H = 512;

  char* ws = (char*)d_ws;
  unsigned short* bufA = (unsigned short*)(ws);                  // 32 MB: X2
  unsigned short* bufB = (unsigned short*)(ws + 33554432);       // 32 MB: X1
  unsigned short* W1t  = (unsigned short*)(ws + 67108864);       // 512 KB
  unsigned short* W2t  = (unsigned short*)(ws + 67633152);       // 512 KB
  unsigned short* W3t  = (unsigned short*)(ws + 68157440);       // 128 KB
  int*    cellStart = (int*)   (ws + 68304896);                  // 16 KB (4096)
  float4* sorted    = (float4*)(ws + 68354048);                  // 128 KB

  // pre: weight transposes + KNN grid build (one launch)
  k_pre<<<dim3(16, 16, 4), 256, 0, stream>>>(W1, W2, W3, W1t, W2t, W3t,
                                             l_pos, cellStart, sorted);

  // GEMM1 + KNN fused (sequential blocks); knn writes d_out, G3 adds
  k_g1knn<<<dim3(1536), 512, 0, stream>>>(emb, W1t, b1, bufB,
                                          h_pos, cellStart, sorted, l_y,
                                          (float*)d_out);

  // GEMM2, GEMM3 (R16 best-known config)
  k_gemm<128, 256, 512, 4, false, true,  true,  false><<<dim3(M/128, 2), 512, 0, stream>>>(bufB, W2t, b2, bufA, H, 512);
  k_gemm<64,  128, 256, 2, false, false, false, true ><<<dim3(M/64,  1), 256, 0, stream>>>(bufA, W3t, b3, d_out, H, 128);
}

// Round 25
// 119.166 us; speedup vs baseline: 1.0081x; 1.0081x over previous
//
#include <hip/hip_runtime.h>
#include <stdint.h>

typedef __attribute__((ext_vector_type(4))) float f32x4;
typedef __attribute__((ext_vector_type(8))) short bf16x8;

#define AS1(p) ((const __attribute__((address_space(1))) void*)(p))
#define AS3(p) ((__attribute__((address_space(3))) void*)(p))

__device__ __forceinline__ unsigned short f2bf(float f){
  unsigned u = __builtin_bit_cast(unsigned, f);
  u += 0x7FFF + ((u >> 16) & 1);     // round-to-nearest-even
  return (unsigned short)(u >> 16);
}

template<int N> __device__ __forceinline__ void waitcnt_vm(){
  if constexpr (N==0) asm volatile("s_waitcnt vmcnt(0)" ::: "memory");
  else if constexpr (N==2) asm volatile("s_waitcnt vmcnt(2)" ::: "memory");
  else if constexpr (N==3) asm volatile("s_waitcnt vmcnt(3)" ::: "memory");
  else if constexpr (N==4) asm volatile("s_waitcnt vmcnt(4)" ::: "memory");
  else if constexpr (N==6) asm volatile("s_waitcnt vmcnt(6)" ::: "memory");
}

// ================= KNN grid geometry ======================================
#define GD 14
#define NL 8192

__device__ __forceinline__ int cellcoord(float x){
  int c = (int)(x * (float)GD);
  return min(GD-1, max(0, c));
}

// ---------- k_pre: 3 weight transposes (z<3) + grid build (z==3) -----------
__global__ __launch_bounds__(256) void k_pre(const float* __restrict__ W1,
                                             const float* __restrict__ W2,
                                             const float* __restrict__ W3,
                                             unsigned short* __restrict__ W1t,
                                             unsigned short* __restrict__ W2t,
                                             unsigned short* __restrict__ W3t,
                                             const float* __restrict__ l_pos,
                                             int* __restrict__ cellStart,
                                             float4* __restrict__ sorted){
  const int z = blockIdx.z;
  if (z == 3){
    if (blockIdx.x != 0 || blockIdx.y != 0) return;
    __shared__ int hist[4096];
    __shared__ int cur[4096];
    __shared__ int s[256];
    const int t = threadIdx.x;
    #pragma unroll
    for (int k = 0; k < 16; k++) hist[k*256 + t] = 0;
    __syncthreads();
    for (int k = 0; k < 32; k++){
      int i = k*256 + t;
      float x = l_pos[3*i], y = l_pos[3*i+1], zz = l_pos[3*i+2];
      int c = (cellcoord(zz)*GD + cellcoord(y))*GD + cellcoord(x);
      atomicAdd(&hist[c], 1);
    }
    __syncthreads();
    int loc[16]; int sum = 0;
    #pragma unroll
    for (int e = 0; e < 16; e++){ loc[e] = hist[t*16 + e]; sum += loc[e]; }
    s[t] = sum;
    __syncthreads();
    for (int off = 1; off < 256; off <<= 1){
      int val = (t >= off) ? s[t-off] : 0;
      __syncthreads();
      s[t] += val;
      __syncthreads();
    }
    int base = s[t] - sum;
    #pragma unroll
    for (int e = 0; e < 16; e++){
      cellStart[t*16 + e] = base;
      cur[t*16 + e] = base;
      base += loc[e];
    }
    __syncthreads();
    for (int k = 0; k < 32; k++){
      int i = k*256 + t;
      float x = l_pos[3*i], y = l_pos[3*i+1], zz = l_pos[3*i+2];
      int c = (cellcoord(zz)*GD + cellcoord(y))*GD + cellcoord(x);
      int slot = atomicAdd(&cur[c], 1);
      float4 q; q.x = x; q.y = y; q.z = zz; q.w = __int_as_float(i);
      sorted[slot] = q;
    }
    return;
  }
  const float* in; unsigned short* out; int R, C;
  if (z == 0){ in = W1; out = W1t; R = 512; C = 512; }
  else if (z == 1){ in = W2; out = W2t; R = 512; C = 512; }
  else { in = W3; out = W3t; R = 512; C = 128; if (blockIdx.x >= 4) return; }
  __shared__ float tile[32][33];
  int tx = threadIdx.x & 31, ty = threadIdx.x >> 5;       // 32 x 8
  int c0 = blockIdx.x*32, r0 = blockIdx.y*32;
  #pragma unroll
  for (int i = 0; i < 4; i++)
    tile[ty + i*8][tx] = in[(size_t)(r0 + ty + i*8)*C + c0 + tx];
  __syncthreads();
  #pragma unroll
  for (int i = 0; i < 4; i++)
    out[(size_t)(c0 + ty + i*8)*R + r0 + tx] = f2bf(tile[tx][ty + i*8]);
}

// ======== GEMM core (R13/R16 proven loop): BM x NC, 3-buf counted-vmcnt ====
// ds_reads at step top, stage t+2 mid, setprio MFMA, counted vmcnt at tail,
// one barrier/step. Chunk swizzle c^((row>>1)&3) both-sides, dest linear.
// AF32: A f32, reg-staged (load early, f2bf+ds_write at tail).
// ADDOUT: out = acc + bias + out_prev (fused knn-interp add).
template<int BM, int NC, int TW, bool AF32, bool RELU, bool OUTBF16, bool ADDOUT>
__device__ __forceinline__ void gemm_core(int bm, int bn, int NOUT,
                                          const void* __restrict__ Av,
                                          const unsigned short* __restrict__ Bt,
                                          const float* __restrict__ bias,
                                          void* __restrict__ out, int K){
  constexpr int WARPS_M = BM/64;
  constexpr int WARPS_N = (TW/64)/WARPS_M;
  constexpr int WN = NC/WARPS_N;
  constexpr int NI = WN/16;
  constexpr int IA = AF32 ? 0 : (BM*4)/TW;
  constexpr int IB = (NC*4)/TW;
  constexpr int LS = IA + IB;

  __shared__ short As[3][BM*32];
  __shared__ short Bs[3][NC*32];

  const int tid  = threadIdx.x;
  const int lane = tid & 63, wid = tid >> 6;
  const int wr = wid / WARPS_N, wc = wid % WARPS_N;
  const int l15 = lane & 15, lk = lane >> 4;

  const unsigned short* Bsrc[IB];
  #pragma unroll
  for (int q = 0; q < IB; q++){
    int row = q*(TW/4) + (tid >> 2);
    int ch  = (tid & 3) ^ ((row >> 1) & 3);
    Bsrc[q] = Bt + (size_t)bn*NC*K + (size_t)row*K + ch*8;
  }
  const unsigned short* Asrc16[IA > 0 ? IA : 1];
  if constexpr (!AF32){
    #pragma unroll
    for (int a = 0; a < IA; a++){
      int row = a*(TW/4) + (tid >> 2);
      int ch  = (tid & 3) ^ ((row >> 1) & 3);
      Asrc16[a] = (const unsigned short*)Av + (size_t)bm*BM*K + (size_t)row*K + ch*8;
    }
  }
  const float* A32 = (const float*)Av + (size_t)bm*BM*K + (size_t)(tid>>2)*K + (size_t)(tid&3)*8;
  const int woff = (tid >> 2)*32 + ((tid & 3) ^ (((tid >> 2) >> 1) & 3))*8;

#define STAGE_B(t_, bb_) do{ int k0_ = (t_) << 5; _Pragma("unroll") \
  for (int q = 0; q < IB; q++) \
    __builtin_amdgcn_global_load_lds(AS1(Bsrc[q] + k0_), AS3(&Bs[bb_][(q*(TW/4))*32 + tid*8]), 16, 0, 0); \
}while(0)
#define STAGE_A16(t_, bb_) do{ int k0_ = (t_) << 5; _Pragma("unroll") \
  for (int a = 0; a < IA; a++) \
    __builtin_amdgcn_global_load_lds(AS1(Asrc16[a] + k0_), AS3(&As[bb_][(a*(TW/4))*32 + tid*8]), 16, 0, 0); \
}while(0)
#define A_CONV_WRITE(bb_) do{ bf16x8 p_; _Pragma("unroll") \
  for (int j_ = 0; j_ < 4; j_++){ p_[j_] = (short)f2bf(ra0[j_]); p_[j_+4] = (short)f2bf(ra1[j_]); } \
  *(bf16x8*)&As[bb_][woff] = p_; \
}while(0)

  f32x4 acc[4][NI];
  #pragma unroll
  for (int i = 0; i < 4; i++)
    #pragma unroll
    for (int j = 0; j < NI; j++) acc[i][j] = (f32x4){0.f,0.f,0.f,0.f};

  const int nt = K >> 5;
  f32x4 ra0, ra1;

  if constexpr (AF32){
    ra0 = *(const f32x4*)(A32);
    ra1 = *(const f32x4*)(A32 + 4);
    STAGE_B(0, 0);
    STAGE_B(1, 1);
    waitcnt_vm<IB>();
    A_CONV_WRITE(0);
    asm volatile("s_waitcnt lgkmcnt(0)" ::: "memory");
  } else {
    STAGE_A16(0, 0); STAGE_B(0, 0);
    STAGE_A16(1, 1); STAGE_B(1, 1);
    waitcnt_vm<LS>();
  }
  __builtin_amdgcn_s_barrier();

  int b = 0;
  for (int t = 0; t < nt; ++t){
    bf16x8 af[4], bg[NI];
    #pragma unroll
    for (int i = 0; i < 4; i++){
      int R = wr*64 + i*16 + l15;
      af[i] = *(const bf16x8*)&As[b][R*32 + (lk ^ ((R >> 1) & 3))*8];
    }
    #pragma unroll
    for (int j = 0; j < NI; j++){
      int R = wc*WN + j*16 + l15;
      bg[j] = *(const bf16x8*)&Bs[b][R*32 + (lk ^ ((R >> 1) & 3))*8];
    }

    int b2 = b + 2; if (b2 >= 3) b2 -= 3;
    if constexpr (AF32){
      if (t + 1 < nt){
        int k1 = (t + 1) << 5;
        ra0 = *(const f32x4*)(A32 + k1);
        ra1 = *(const f32x4*)(A32 + k1 + 4);
      }
      if (t + 2 < nt) STAGE_B(t + 2, b2);
    } else {
      if (t + 2 < nt){ STAGE_A16(t + 2, b2); STAGE_B(t + 2, b2); }
    }

    __builtin_amdgcn_s_setprio(1);
    #pragma unroll
    for (int i = 0; i < 4; i++)
      #pragma unroll
      for (int j = 0; j < NI; j++)
        acc[i][j] = __builtin_amdgcn_mfma_f32_16x16x32_bf16(af[i], bg[j], acc[i][j], 0, 0, 0);
    __builtin_amdgcn_s_setprio(0);

    if (t + 2 < nt) waitcnt_vm<(AF32 ? IB : LS)>();
    else            waitcnt_vm<0>();
    if constexpr (AF32){
      if (t + 1 < nt){
        int wb = b + 1; if (wb >= 3) wb -= 3;
        A_CONV_WRITE(wb);
      }
    }
    asm volatile("s_waitcnt lgkmcnt(0)" ::: "memory");
    __builtin_amdgcn_s_barrier();
    b = (b + 1 == 3) ? 0 : b + 1;
  }
#undef STAGE_B
#undef STAGE_A16
#undef A_CONV_WRITE

  const int row0 = bm*BM + wr*64 + lk*4;
  const int col0 = bn*NC + wc*WN + l15;
  #pragma unroll
  for (int i = 0; i < 4; i++){
    #pragma unroll
    for (int j = 0; j < NI; j++){
      int col = col0 + j*16;
      float bv = bias[col];
      #pragma unroll
      for (int r = 0; r < 4; r++){
        int row = row0 + i*16 + r;
        float v = acc[i][j][r] + bv;
        if (RELU) v = fmaxf(v, 0.f);
        if (ADDOUT) v = v + ((const float*)out)[(size_t)row*NOUT + col];
        if (OUTBF16) ((unsigned short*)out)[(size_t)row*NOUT + col] = f2bf(v);
        else         ((float*)out)[(size_t)row*NOUT + col] = v;
      }
    }
  }
}

template<int BM, int NC, int TW, int MINW, bool AF32, bool RELU, bool OUTBF16, bool ADDOUT>
__global__ __launch_bounds__(TW, MINW) void k_gemm(const void* __restrict__ Av,
                                                   const unsigned short* __restrict__ Bt,
                                                   const float* __restrict__ bias,
                                                   void* __restrict__ out, int K, int NOUT){
  gemm_core<BM, NC, TW, AF32, RELU, OUTBF16, ADDOUT>(blockIdx.x, blockIdx.y, NOUT,
                                                     Av, Bt, bias, out, K);
}

// ================= KNN search + gather core ================================
// Dedup-safe + (d, index)-lexicographic insert: order-independent top-3
#define KNN_INS(dv, gi) \
  if (gi != i0 && gi != i1 && gi != i2 && \
      (dv < d2 || (dv == d2 && gi < i2))){ \
    if (dv < d1 || (dv == d1 && gi < i1)){ \
      d2 = d1; i2 = i1; \
      if (dv < d0 || (dv == d0 && gi < i0)){ d1 = d0; i1 = i0; d0 = dv; i0 = gi; } \
      else { d1 = dv; i1 = gi; } \
    } else { d2 = dv; i2 = gi; } \
  }

#define KNN_MERGE16() \
  _Pragma("unroll") \
  for (int m = 1; m < 16; m <<= 1){ \
    float e0 = __shfl_xor(d0, m), e1 = __shfl_xor(d1, m), e2 = __shfl_xor(d2, m); \
    int   j0 = __shfl_xor(i0, m), j1 = __shfl_xor(i1, m), j2 = __shfl_xor(i2, m); \
    KNN_INS(e0, j0); KNN_INS(e1, j1); KNN_INS(e2, j2); \
  }

// 16 lanes per h-point: search top-3 AND gather/interp (fused, no wts/idx).
__device__ __forceinline__ void knn_core(int h, int sl,
                                         const float* __restrict__ h_pos,
                                         const int* __restrict__ cellStart,
                                         const float4* __restrict__ sorted,
                                         const float* __restrict__ l_y,
                                         float* __restrict__ out){
  const float hx = h_pos[3*h], hy = h_pos[3*h+1], hz = h_pos[3*h+2];
  const int cx = cellcoord(hx), cy = cellcoord(hy), cz = cellcoord(hz);
  const float cs = 1.0f/(float)GD;
  float d0 = 3e38f, d1 = 3e38f, d2 = 3e38f;
  int   i0 = 0x7fffffff, i1 = 0x7fffffff, i2 = 0x7fffffff;

  for (int ci = sl; ci < 27; ci += 16){
    int dz = ci/9 - 1, dy = (ci - (ci/9)*9)/3 - 1, dx = ci % 3 - 1;
    int zz = cz+dz, yy = cy+dy, xx = cx+dx;
    if ((unsigned)zz >= GD || (unsigned)yy >= GD || (unsigned)xx >= GD) continue;
    int c = (zz*GD + yy)*GD + xx;
    int p0 = cellStart[c], p1 = cellStart[c+1];
    for (int p = p0; p < p1; p++){
      float4 qq = sorted[p];
      float ddx = hx - qq.x, ddy = hy - qq.y, ddz = hz - qq.z;
      float d = fmaf(ddx, ddx, fmaf(ddy, ddy, ddz*ddz));
      int gi = __float_as_int(qq.w);
      KNN_INS(d, gi);
    }
  }
  KNN_MERGE16();

  for (int r = 2; r < GD; r++){
    int rp = r - 1;
    float B = 3e38f;
    if (cx - rp > 0)      B = fminf(B, hx - (float)(cx-rp)*cs);
    if (cx + rp + 1 < GD) B = fminf(B, (float)(cx+rp+1)*cs - hx);
    if (cy - rp > 0)      B = fminf(B, hy - (float)(cy-rp)*cs);
    if (cy + rp + 1 < GD) B = fminf(B, (float)(cy+rp+1)*cs - hy);
    if (cz - rp > 0)      B = fminf(B, hz - (float)(cz-rp)*cs);
    if (cz + rp + 1 < GD) B = fminf(B, (float)(cz+rp+1)*cs - hz);
    if (d2 <= B*B) break;                     // group-uniform after merge

    int side = 2*r + 1, ss = side*side, tot = ss*side;
    for (int ci = sl; ci < tot; ci += 16){
      int dz = ci/ss - r;
      int rem = ci - (ci/ss)*ss;
      int dy = rem/side - r, dx = rem - (rem/side)*side - r;
      int adx = abs(dx), ady = abs(dy), adz = abs(dz);
      if (max(adx, max(ady, adz)) < r) continue;   // shell-exact
      int zz = cz+dz, yy = cy+dy, xx = cx+dx;
      if ((unsigned)zz >= GD || (unsigned)yy >= GD || (unsigned)xx >= GD) continue;
      int c = (zz*GD + yy)*GD + xx;
      int p0 = cellStart[c], p1 = cellStart[c+1];
      for (int p = p0; p < p1; p++){
        float4 qq = sorted[p];
        float ddx = hx - qq.x, ddy = hy - qq.y, ddz = hz - qq.z;
        float d = fmaf(ddx, ddx, fmaf(ddy, ddy, ddz*ddz));
        int gi = __float_as_int(qq.w);
        KNN_INS(d, gi);
      }
    }
    KNN_MERGE16();
  }

  // fused gather: lane sl handles feats [sl*8, sl*8+8) = 2 f32x4
  float w0 = 1.0f/fmaxf(d0, 1e-16f);
  float w1 = 1.0f/fmaxf(d1, 1e-16f);
  float w2 = 1.0f/fmaxf(d2, 1e-16f);
  float inv = 1.0f/(w0 + w1 + w2);
  const f32x4* ly4 = (const f32x4*)l_y;
  size_t b0 = (size_t)i0*32 + sl*2;
  size_t b1 = (size_t)i1*32 + sl*2;
  size_t b2 = (size_t)i2*32 + sl*2;
  f32x4 a0 = ly4[b0]*w0     + ly4[b1]*w1     + ly4[b2]*w2;
  f32x4 a1 = ly4[b0 + 1]*w0 + ly4[b1 + 1]*w1 + ly4[b2 + 1]*w2;
  size_t o = (size_t)h*32 + sl*2;
  ((f32x4*)out)[o]     = a0*inv;
  ((f32x4*)out)[o + 1] = a1*inv;
}

// ======== Fused GEMM1 + KNN: heterogeneous blocks (best measured) ==========
// grid 1536: gid%3==0 -> GEMM1 block (512 total); else knn block (1024 x 32
// h-points, no barriers).
__global__ __launch_bounds__(512, 4) void k_g1knn(const float* __restrict__ emb,
                                                  const unsigned short* __restrict__ W1t,
                                                  const float* __restrict__ b1,
                                                  unsigned short* __restrict__ bufB,
                                                  const float* __restrict__ h_pos,
                                                  const int* __restrict__ cellStart,
                                                  const float4* __restrict__ sorted,
                                                  const float* __restrict__ l_y,
                                                  float* __restrict__ dout){
  const int gid = blockIdx.x;
  const int m3 = gid % 3;
  if (m3 == 0){
    int g = gid / 3;
    gemm_core<128, 256, 512, true, true, true, false>(g >> 1, g & 1, 512,
                                                      emb, W1t, b1, bufB, 512);
  } else {
    int k = (gid / 3)*2 + m3 - 1;           // 0..1023
    int t = threadIdx.x;
    knn_core(k*32 + (t >> 4), t & 15, h_pos, cellStart, sorted, l_y, dout);
  }
}

extern "C" void kernel_launch(void* const* d_in, const int* in_sizes, int n_in,
                              void* d_out, int out_size, void* d_ws, size_t ws_size,
                              hipStream_t stream){
  const float* emb   = (const float*)d_in[0];
  const float* l_y   = (const float*)d_in[1];
  const float* l_pos = (const float*)d_in[2];
  const float* h_pos = (const float*)d_in[3];
  const float* W1    = (const float*)d_in[4];
  const float* b1    = (const float*)d_in[5];
  const float* W2    = (const float*)d_in[6];
  const float* b2    = (const float*)d_in[7];
  const float* W3    = (const float*)d_in[8];
  const float* b3    = (const float*)d_in[9];

  const int M = 32768, H = 512;

  char* ws = (char*)d_ws;
  unsigned short* bufA = (unsigned short*)(ws);                  // 32 MB: X2
  unsigned short* bufB = (unsigned short*)(ws + 33554432);       // 32 MB: X1
  unsigned short* W1t  = (unsigned short*)(ws + 67108864);       // 512 KB
  unsigned short* W2t  = (unsigned short*)(ws + 67633152);       // 512 KB
  unsigned short* W3t  = (unsigned short*)(ws + 68157440);       // 128 KB
  int*    cellStart = (int*)   (ws + 68304896);                  // 16 KB (4096)
  float4* sorted    = (float4*)(ws + 68354048);                  // 128 KB

  // pre: weight transposes + KNN grid build (one launch)
  k_pre<<<dim3(16, 16, 4), 256, 0, stream>>>(W1, W2, W3, W1t, W2t, W3t,
                                             l_pos, cellStart, sorted);

  // GEMM1 + KNN fused (heterogeneous blocks); knn writes d_out, G3 adds
  k_g1knn<<<dim3(1536), 512, 0, stream>>>(emb, W1t, b1, bufB,
                                          h_pos, cellStart, sorted, l_y,
                                          (float*)d_out);

  // GEMM2, GEMM3 (R16 best-known config)
  k_gemm<128, 256, 512, 4, false, true,  true,  false><<<dim3(M/128, 2), 512, 0, stream>>>(bufB, W2t, b2, bufA, H, 512);
  k_gemm<64,  128, 256, 2, false, false, false, true ><<<dim3(M/64,  1), 256, 0, stream>>>(bufA, W3t, b3, d_out, H, 128);
}